// Round 9
// baseline (161.814 us; speedup 1.0000x reference)
//
#include <hip/hip_runtime.h>
#include <hip/hip_bf16.h>

#define BATCH 4
#define CHAN 128
#define HGT 96
#define WID 160
#define HW (HGT * WID)
#define THREADS 256

typedef __attribute__((ext_vector_type(8))) short short8;
typedef __attribute__((ext_vector_type(4))) float float4v;

// Output channel index for displacement (dy,dx), matching _displacements(4) order.
__device__ __forceinline__ int chan_of(int dy, int dx) {
    if (dy == 0 && dx == 0) return 0;
    if (dx == 0) { int i = dy < 0 ? -dy : dy; return 1 + (i - 1) * 20 + (dy < 0 ? 0 : 1); }
    if (dy == 0) { int i = dx < 0 ? -dx : dx; return 1 + (i - 1) * 20 + (dx < 0 ? 2 : 3); }
    int i = dy < 0 ? -dy : dy;
    int j = dx < 0 ? -dx : dx;
    int s = (dy < 0) ? (dx < 0 ? 0 : 2) : (dx < 0 ? 3 : 1);
    return 1 + (i - 1) * 20 + 4 + (j - 1) * 4 + s;
}

// Packed fp32x2 -> bf16x2 (gfx950 v_cvt_pk_bf16_f32): 1 VALU per 2 elements
// vs 4/element for the manual RNE sequence (R8's VALUBusy=42% culprit).
__device__ __forceinline__ unsigned pk2(float a, float b) {
    __hip_bfloat162 h = __float22bfloat162_rn(make_float2(a, b));
    unsigned u;
    __builtin_memcpy(&u, &h, 4);
    return u;
}

union frag_u { unsigned u[4]; short8 s; };

// Gather-MFMA cost volume. Wave = (b, y, x-tile16), all 9 dy in-loop with
// per-dy epilogue (acc live = 8 VGPR). waves_per_eu(4,4): 128-VGPR cap, live
// set ~90 -> no restaging, 16-deep gather batches preserved (R8: VGPR=44
// restaged everything).
__global__ __launch_bounds__(THREADS)
__attribute__((amdgpu_waves_per_eu(4, 4)))
void cost_volume_kernel(const float* __restrict__ src,
                        const float* __restrict__ tgt,
                        float* __restrict__ out) {
    const int tid  = threadIdx.x;
    const int wid  = tid >> 6;        // wave -> y offset within quad
    const int lane = tid & 63;
    const int q    = lane >> 4;       // quad
    const int ln   = lane & 15;       // m (A) / n (B) lane index

    // XCD-affinity swizzle (validated R6): blockIdx%8 -> (batch, y-half) slab.
    const int w    = blockIdx.x;      // 0..959
    const int slab = w & 7;
    const int b    = slab >> 1;
    const int yh   = slab & 1;
    const int r    = w >> 3;          // 0..119
    const int xt   = r / 12;          // 0..9
    const int yq   = r % 12;          // 0..11
    const int x0   = xt * 16;
    const int y    = yh * 48 + yq * 4 + wid;

    const int kb = q * 8 * HW;        // per-lane k-octet base (channel) offset

    // ---- A fragments: A[m=ln][k=q*8+j] = src[b, k, y, x0+ln]; reused 9x ----
    // readfirstlane forces the wave-uniform row offset into an SGPR -> saddr
    // loads (1 VALU/load instead of 2 for 64-bit vector adds).
    const int sb_off = __builtin_amdgcn_readfirstlane((b * CHAN * HGT + y) * WID);
    const float* sbase = src + sb_off;
    short8 afr[4];
    #pragma unroll
    for (int ks = 0; ks < 4; ++ks) {
        float av[8];
        #pragma unroll
        for (int j = 0; j < 8; ++j)
            av[j] = sbase[x0 + ln + kb + (ks * 32 + j) * HW];
        frag_u f;
        #pragma unroll
        for (int jj = 0; jj < 4; ++jj)
            f.u[jj] = pk2(av[2 * jj], av[2 * jj + 1]);
        afr[ks] = f.s;
    }

    // lane x' per N-tile (clamped; OOB lanes zero their fragment -> zero-pad)
    const int  xq0  = x0 - 4 + ln;
    const int  xq1  = x0 + 12 + ln;
    const bool xok0 = (unsigned)xq0 < (unsigned)WID;
    const bool xok1 = (unsigned)xq1 < (unsigned)WID;
    const int  xc0  = (xok0 ? xq0 : 0) + kb;
    const int  xc1  = (xok1 ? xq1 : 0) + kb;

    const float inv = 1.0f / 81.0f;

    #pragma unroll 1
    for (int dyi = 0; dyi < 9; ++dyi) {
        const int dy  = dyi - 4;
        const int row = y + dy;                 // wave-uniform
        float4v acc0 = (float4v){0.f, 0.f, 0.f, 0.f};
        float4v acc1 = (float4v){0.f, 0.f, 0.f, 0.f};

        if ((unsigned)row < (unsigned)HGT) {
            const int tb_off =
                __builtin_amdgcn_readfirstlane((b * CHAN * HGT + row) * WID);
            const float* t0 = tgt + tb_off + xc0;
            const float* t1 = tgt + tb_off + xc1;
            #pragma unroll
            for (int ks = 0; ks < 4; ++ks) {
                // 16 independent dword gathers in flight, then 2 MFMAs
                float b0[8], b1[8];
                #pragma unroll
                for (int j = 0; j < 8; ++j)
                    b0[j] = t0[(ks * 32 + j) * HW];
                #pragma unroll
                for (int j = 0; j < 8; ++j)
                    b1[j] = t1[(ks * 32 + j) * HW];
                frag_u f0, f1;
                #pragma unroll
                for (int jj = 0; jj < 4; ++jj) {
                    f0.u[jj] = xok0 ? pk2(b0[2 * jj], b0[2 * jj + 1]) : 0u;
                    f1.u[jj] = xok1 ? pk2(b1[2 * jj], b1[2 * jj + 1]) : 0u;
                }
                acc0 = __builtin_amdgcn_mfma_f32_16x16x32_bf16(
                    afr[ks], f0.s, acc0, 0, 0, 0);
                acc1 = __builtin_amdgcn_mfma_f32_16x16x32_bf16(
                    afr[ks], f1.s, acc1, 0, 0, 0);
            }
        }
        // row OOB: acc stays 0 -> writes the required zeros

        // ---- per-dy epilogue: C/D layout col(n=x')=ln, row(m)=q*4+reg ----
        #pragma unroll
        for (int reg = 0; reg < 4; ++reg) {
            const int m = q * 4 + reg;          // output x = x0 + m
            {   // nt = 0
                int dx = ln - 4 - m;
                if (dx >= -4 && dx <= 4) {      // exec-masked scatter store
                    int oc = chan_of(dy, dx);
                    out[((b * 81 + oc) * HGT + y) * WID + x0 + m] = acc0[reg] * inv;
                }
            }
            {   // nt = 1
                int dx = 16 + ln - 4 - m;
                if (dx >= -4 && dx <= 4) {
                    int oc = chan_of(dy, dx);
                    out[((b * 81 + oc) * HGT + y) * WID + x0 + m] = acc1[reg] * inv;
                }
            }
        }
    }
}

extern "C" void kernel_launch(void* const* d_in, const int* in_sizes, int n_in,
                              void* d_out, int out_size, void* d_ws, size_t ws_size,
                              hipStream_t stream) {
    const float* src = (const float*)d_in[0];
    const float* tgt = (const float*)d_in[1];
    float* out = (float*)d_out;
    cost_volume_kernel<<<dim3(960, 1, 1), dim3(THREADS, 1, 1), 0, stream>>>(src, tgt, out);
}

// Round 10
// 127.657 us; speedup vs baseline: 1.2676x; 1.2676x over previous
//
#include <hip/hip_runtime.h>
#include <hip/hip_bf16.h>

#define BATCH 4
#define CHAN 128
#define HGT 96
#define WID 160
#define HW (HGT * WID)
#define THREADS 256

typedef __attribute__((ext_vector_type(8))) short short8;
typedef __attribute__((ext_vector_type(4))) float float4v;

// Output channel index for displacement (dy,dx), matching _displacements(4) order.
__device__ __forceinline__ int chan_of(int dy, int dx) {
    if (dy == 0 && dx == 0) return 0;
    if (dx == 0) { int i = dy < 0 ? -dy : dy; return 1 + (i - 1) * 20 + (dy < 0 ? 0 : 1); }
    if (dy == 0) { int i = dx < 0 ? -dx : dx; return 1 + (i - 1) * 20 + (dx < 0 ? 2 : 3); }
    int i = dy < 0 ? -dy : dy;
    int j = dx < 0 ? -dx : dx;
    int s = (dy < 0) ? (dx < 0 ? 0 : 2) : (dx < 0 ? 3 : 1);
    return 1 + (i - 1) * 20 + 4 + (j - 1) * 4 + s;
}

// Packed fp32x2 -> bf16x2 (v_cvt_pk_bf16_f32).
__device__ __forceinline__ unsigned pk2(float a, float b) {
    __hip_bfloat162 h = __float22bfloat162_rn(make_float2(a, b));
    unsigned u;
    __builtin_memcpy(&u, &h, 4);
    return u;
}

union sl_u { uint4 v; short8 s; };

// LDS-staged MFMA cost volume. Block = (b, 4-row y-quad, 16-x tile, dy-triplet).
// tgt window (6 rows x 24 x x 128 c) staged ONCE as bf16 c-octets with
// XOR-swizzled 16B slots -> staging writes and fragment reads both spread
// uniformly across all 32 banks. One barrier per block; MFMA loop branch-free
// (OOB rows/cols zeroed in LDS = reference zero-pad). R7-R9 lesson: register
// MLP is not source-controllable; LDS short-latency reads are.
__global__ __launch_bounds__(THREADS)
void cost_volume_kernel(const float* __restrict__ src,
                        const float* __restrict__ tgt,
                        float* __restrict__ out) {
    // B tile: 6 rows x 24 x x 16 octets = 2304 slots; sized 2432 so nt=1
    // fragment reads at x up to 31 (band-masked-off columns) stay in-bounds.
    __shared__ __align__(16) uint4 s_b[2432];   // 38912 B -> 4 blocks/CU

    const int tid  = threadIdx.x;
    const int wv   = tid >> 6;        // wave -> y offset in quad
    const int lane = tid & 63;
    const int q    = lane >> 4;       // quad
    const int ln   = lane & 15;       // m (A) / n (B) lane index

    // XCD-affinity swizzle (validated R6): blockIdx%8 -> (batch, y-half) slab.
    const int w    = blockIdx.x;      // 0..2879
    const int slab = w & 7;
    const int b    = slab >> 1;
    const int yh   = slab & 1;
    const int r0   = w >> 3;          // 0..359
    const int dyg  = r0 % 3;
    const int t    = r0 / 3;          // 0..119
    const int x0   = (t % 10) * 16;
    const int y0   = yh * 48 + (t / 10) * 4;
    const int dy0  = dyg * 3 - 4;     // dys: dy0 .. dy0+2

    // ---- stage B (tgt) tile: 2304 octet-tasks, 9 per thread ----
    #pragma unroll
    for (int k = 0; k < 9; ++k) {
        const int u   = k * THREADS + tid;   // 0..2303
        const int x   = u % 24;              // lanes span x -> coalesced
        const int g   = u / 24;              // 0..95
        const int row = g % 6;
        const int oct = g / 6;               // c-octet 0..15
        const int gr  = y0 + dy0 + row;
        const int gx  = x0 - 4 + x;
        uint4 val = make_uint4(0u, 0u, 0u, 0u);
        if ((unsigned)gr < (unsigned)HGT && (unsigned)gx < (unsigned)WID) {
            const int off = ((b * CHAN + oct * 8) * HGT + gr) * WID + gx;
            float v0 = tgt[off];
            float v1 = tgt[off + 1 * HW];
            float v2 = tgt[off + 2 * HW];
            float v3 = tgt[off + 3 * HW];
            float v4 = tgt[off + 4 * HW];
            float v5 = tgt[off + 5 * HW];
            float v6 = tgt[off + 6 * HW];
            float v7 = tgt[off + 7 * HW];
            val.x = pk2(v0, v1);
            val.y = pk2(v2, v3);
            val.z = pk2(v4, v5);
            val.w = pk2(v6, v7);
        }
        s_b[(row * 24 + x) * 16 + (oct ^ (x & 15))] = val;
    }

    // ---- A fragments: direct gather (R9-validated), overlaps staging ----
    const int y  = y0 + wv;
    const int sb = (b * CHAN * HGT + y) * WID + x0 + ln + q * 8 * HW;
    short8 afr[4];
    #pragma unroll
    for (int ks = 0; ks < 4; ++ks) {
        float av[8];
        #pragma unroll
        for (int j = 0; j < 8; ++j)
            av[j] = src[sb + (ks * 32 + j) * HW];
        sl_u f;
        f.v.x = pk2(av[0], av[1]);
        f.v.y = pk2(av[2], av[3]);
        f.v.z = pk2(av[4], av[5]);
        f.v.w = pk2(av[6], av[7]);
        afr[ks] = f.s;
    }

    __syncthreads();

    // ---- compute + per-dy epilogue: 24 ds_read_b128 + 24 MFMA per wave ----
    const float inv = 1.0f / 81.0f;
    #pragma unroll
    for (int dyi = 0; dyi < 3; ++dyi) {
        const int dy = dy0 + dyi;
        const int rr = wv + dyi;              // LDS row = (y+dy) - (y0+dy0)
        float4v a0 = (float4v){0.f, 0.f, 0.f, 0.f};
        float4v a1 = (float4v){0.f, 0.f, 0.f, 0.f};
        #pragma unroll
        for (int ks = 0; ks < 4; ++ks) {
            sl_u b0;   // nt=0: x index = ln (x&15 = ln)
            b0.v = s_b[(rr * 24 + ln) * 16 + ((q + ks * 4) ^ ln)];
            a0 = __builtin_amdgcn_mfma_f32_16x16x32_bf16(afr[ks], b0.s, a0, 0, 0, 0);
        }
        #pragma unroll
        for (int ks = 0; ks < 4; ++ks) {
            sl_u b1;   // nt=1: x index = 16+ln ((16+ln)&15 = ln)
            b1.v = s_b[(rr * 24 + 16 + ln) * 16 + ((q + ks * 4) ^ ln)];
            a1 = __builtin_amdgcn_mfma_f32_16x16x32_bf16(afr[ks], b1.s, a1, 0, 0, 0);
        }
        // band extraction from C/D layout (col=n=ln, row=m=q*4+reg)
        #pragma unroll
        for (int reg = 0; reg < 4; ++reg) {
            const int m = q * 4 + reg;        // output x = x0 + m
            {   // nt = 0
                int dx = ln - 4 - m;
                if (dx >= -4 && dx <= 4) {
                    int oc = chan_of(dy, dx);
                    out[((b * 81 + oc) * HGT + y) * WID + x0 + m] = a0[reg] * inv;
                }
            }
            {   // nt = 1
                int dx = 16 + ln - 4 - m;
                if (dx >= -4 && dx <= 4) {
                    int oc = chan_of(dy, dx);
                    out[((b * 81 + oc) * HGT + y) * WID + x0 + m] = a1[reg] * inv;
                }
            }
        }
    }
}

extern "C" void kernel_launch(void* const* d_in, const int* in_sizes, int n_in,
                              void* d_out, int out_size, void* d_ws, size_t ws_size,
                              hipStream_t stream) {
    const float* src = (const float*)d_in[0];
    const float* tgt = (const float*)d_in[1];
    float* out = (float*)d_out;
    cost_volume_kernel<<<dim3(2880, 1, 1), dim3(THREADS, 1, 1), 0, stream>>>(src, tgt, out);
}